// Round 1
// baseline (84143.970 us; speedup 1.0000x reference)
//
#include <hip/hip_runtime.h>
#include <cmath>

// ESN forward scan on MI355X.
// Design: persistent cooperative kernel, 256 blocks x 256 threads (1 block/CU,
// forced by 139 KB LDS). Each block owns 16 rows of Wh, converted fp32->fp16
// into LDS ONCE per launch (fp16 not bf16: need the 11-bit mantissa; weights
// ~±0.034 so range is no issue). Per step: stage h (global fp32 -> LDS fp16),
// dot via v_dot2_f32_f16 with fp32 accum, wave-butterfly reduce, tanh+leak on
// lanes 0..3, write h ping-pong + output row, then a custom grid barrier
// (monotone arrival counter in d_ws; __threadfence gives the wbl2/inv needed
// for cross-XCD visibility of the h buffers).

#define T_STEPS  4096
#define R_SIZE   4096
#define I_SIZE   3
#define OUT_COLS (R_SIZE + I_SIZE)   // 4099
#define NB       256                 // blocks == CUs; all co-resident
#define BT       256                 // threads per block (4 waves)
#define RPB      16                  // rows per block
#define RPW      4                   // rows per wave
#define LEAK     0.1f

typedef _Float16 h2 __attribute__((ext_vector_type(2)));
typedef _Float16 h4 __attribute__((ext_vector_type(4)));
typedef _Float16 h8 __attribute__((ext_vector_type(8)));

__device__ __forceinline__ float fdot2f(h2 a, h2 b, float c) {
#if __has_builtin(__builtin_amdgcn_fdot2)
    return __builtin_amdgcn_fdot2(a, b, c, false);
#else
    return c + (float)a[0] * (float)b[0] + (float)a[1] * (float)b[1];
#endif
}

__global__ void __launch_bounds__(BT, 1) esn_kernel(
    const float* __restrict__ Wh,   // [R, R] row-major
    const float* __restrict__ Win,  // [R, 3]
    const float* __restrict__ x,    // [T, 3]
    float* __restrict__ out,        // [T, 4099]
    float* __restrict__ hbuf,       // 2*R floats, zeroed by memset
    unsigned* __restrict__ bar)     // arrival counter, zeroed by memset
{
    __shared__ alignas(16) _Float16 whl[RPB][R_SIZE];  // 128 KB
    __shared__ alignas(16) _Float16 hl[R_SIZE];        // 8 KB
    __shared__ float winl[RPB][3];

    const int tid  = threadIdx.x;
    const int bid  = blockIdx.x;
    const int wv   = tid >> 6;
    const int lane = tid & 63;
    const int r0   = bid * RPB;

    // ---- one-time: stage this block's 16 Wh rows into LDS as fp16 ----
    for (int rr = 0; rr < RPB; ++rr) {
        const float4* src = (const float4*)(Wh + (size_t)(r0 + rr) * R_SIZE);
        h4* dst = (h4*)&whl[rr][0];
        #pragma unroll
        for (int jj = 0; jj < R_SIZE / 4 / BT; ++jj) {   // 4 iters
            int i4 = jj * BT + tid;
            float4 v = src[i4];
            h4 hv;
            hv[0] = (_Float16)v.x; hv[1] = (_Float16)v.y;
            hv[2] = (_Float16)v.z; hv[3] = (_Float16)v.w;
            dst[i4] = hv;
        }
    }
    if (tid < RPB * I_SIZE) {
        int rr = tid / I_SIZE, c = tid % I_SIZE;
        winl[rr][c] = Win[(size_t)(r0 + rr) * I_SIZE + c];
    }
    __syncthreads();

    float* h0p = hbuf;
    float* h1p = hbuf + R_SIZE;

    for (int t = 0; t < T_STEPS; ++t) {
        const float* hcur = (t & 1) ? h1p : h0p;
        float*       hnxt = (t & 1) ? h0p : h1p;

        // x_t (same address across lanes -> broadcast load; L2 gets
        // invalidated each barrier so this re-reads L3 — 12 B, fine)
        const float xt0 = x[t * 3 + 0];
        const float xt1 = x[t * 3 + 1];
        const float xt2 = x[t * 3 + 2];

        // ---- stage h (fp32 global -> fp16 LDS) ----
        {
            const float4* hg4 = (const float4*)hcur;
            h4* hld = (h4*)hl;
            #pragma unroll
            for (int jj = 0; jj < R_SIZE / 4 / BT; ++jj) {   // 4 iters
                int i4 = jj * BT + tid;
                float4 v = hg4[i4];
                h4 hv;
                hv[0] = (_Float16)v.x; hv[1] = (_Float16)v.y;
                hv[2] = (_Float16)v.z; hv[3] = (_Float16)v.w;
                hld[i4] = hv;
            }
        }
        __syncthreads();

        // ---- per-lane h chunk into registers (reused across 4 rows) ----
        h8 hreg[8];
        const h8* hl8 = (const h8*)hl;
        #pragma unroll
        for (int j = 0; j < 8; ++j) hreg[j] = hl8[j * 64 + lane];

        // ---- 4 rows per wave: LDS-stream Wh, dot2-accumulate ----
        float acc[RPW];
        #pragma unroll
        for (int rr = 0; rr < RPW; ++rr) {
            const h8* wrow = (const h8*)&whl[wv * RPW + rr][0];
            float a = 0.0f;
            #pragma unroll
            for (int j = 0; j < 8; ++j) {
                h8 w8 = wrow[j * 64 + lane];
                h8 hh = hreg[j];
                a = fdot2f(__builtin_shufflevector(w8, w8, 0, 1),
                           __builtin_shufflevector(hh, hh, 0, 1), a);
                a = fdot2f(__builtin_shufflevector(w8, w8, 2, 3),
                           __builtin_shufflevector(hh, hh, 2, 3), a);
                a = fdot2f(__builtin_shufflevector(w8, w8, 4, 5),
                           __builtin_shufflevector(hh, hh, 4, 5), a);
                a = fdot2f(__builtin_shufflevector(w8, w8, 6, 7),
                           __builtin_shufflevector(hh, hh, 6, 7), a);
            }
            #pragma unroll
            for (int s = 32; s; s >>= 1) a += __shfl_xor(a, s, 64);
            acc[rr] = a;   // butterfly: all lanes hold the row sum
        }

        // ---- epilogue: lanes 0..3 each finish one row ----
        if (lane < RPW) {
            int rr = wv * RPW + lane;
            float a = (lane == 0) ? acc[0]
                    : (lane == 1) ? acc[1]
                    : (lane == 2) ? acc[2] : acc[3];
            float u  = xt0 * winl[rr][0] + xt1 * winl[rr][1] + xt2 * winl[rr][2];
            float hn = tanhf(u + a);
            int   r  = r0 + rr;
            float hold = (float)hl[r];            // fp16 h_cur; leak term err ~2e-5
            float hv = LEAK * hold + (1.0f - LEAK) * hn;
            hnxt[r] = hv;
            out[(size_t)t * OUT_COLS + r] = hv;
        }

        // ---- grid barrier (monotone counter, no reset -> no reuse race) ----
        __syncthreads();
        if (tid == 0) {
            __threadfence();   // release: drain + wbl2 -> h stores reach coherence pt
            __hip_atomic_fetch_add(bar, 1u, __ATOMIC_RELAXED, __HIP_MEMORY_SCOPE_AGENT);
            const unsigned target = (unsigned)(t + 1) * NB;   // max 1,048,576 < 2^32
            while (__hip_atomic_load(bar, __ATOMIC_RELAXED, __HIP_MEMORY_SCOPE_AGENT) < target)
                __builtin_amdgcn_s_sleep(1);
            __threadfence();   // acquire: inv L1/L2 so stale h ping-pong lines die
        }
        __syncthreads();
    }
}

__global__ void copy_x_kernel(const float* __restrict__ x, float* __restrict__ out) {
    int i = blockIdx.x * blockDim.x + threadIdx.x;
    if (i < T_STEPS * I_SIZE) {
        int t = i / I_SIZE, c = i % I_SIZE;
        out[(size_t)t * OUT_COLS + R_SIZE + c] = x[i];
    }
}

extern "C" void kernel_launch(void* const* d_in, const int* in_sizes, int n_in,
                              void* d_out, int out_size, void* d_ws, size_t ws_size,
                              hipStream_t stream) {
    // setup_inputs order: x [T,3], Win [R,3], Wh [R,R]; all fp32.
    const float* x   = (const float*)d_in[0];
    const float* Win = (const float*)d_in[1];
    const float* Wh  = (const float*)d_in[2];
    float* out = (float*)d_out;

    // ws layout: h ping-pong (2*R floats = 32 KB) + barrier counter.
    float*    hbuf = (float*)d_ws;
    unsigned* bar  = (unsigned*)((char*)d_ws + 2 * R_SIZE * sizeof(float));

    // zero h0 (reference h0 = 0) and the barrier counter (ws is poisoned 0xAA)
    hipMemsetAsync(d_ws, 0, 2 * R_SIZE * sizeof(float) + 256, stream);

    copy_x_kernel<<<dim3((T_STEPS * I_SIZE + BT - 1) / BT), dim3(BT), 0, stream>>>(x, out);

    void* args[] = {(void*)&Wh, (void*)&Win, (void*)&x, (void*)&out,
                    (void*)&hbuf, (void*)&bar};
    hipError_t e = hipLaunchCooperativeKernel((void*)esn_kernel, dim3(NB), dim3(BT),
                                              args, 0, stream);
    if (e != hipSuccess) {
        // Fallback: plain launch. 139 KB LDS forces 1 block/CU and grid==CU
        // count, so all 256 blocks are co-resident in practice; the custom
        // barrier remains valid.
        esn_kernel<<<dim3(NB), dim3(BT), 0, stream>>>(Wh, Win, x, out, hbuf, bar);
    }
}

// Round 2
// 24558.105 us; speedup vs baseline: 3.4263x; 3.4263x over previous
//
#include <hip/hip_runtime.h>
#include <cmath>

// ESN forward scan on MI355X — round 2.
// Round-1 lesson (rocprof): single-counter grid barrier + per-step
// __threadfence = ~20 us/step of pure sync latency (VALUBusy 1.8%).
// Round-2 design: fence-free dataflow exchange. Each h element is published
// as one dword: (step_tag << 16) | fp16_bits(h). Writers use relaxed
// AGENT-scope atomic stores (write-through to the coherence point, no RMW,
// no contention); readers poll with relaxed AGENT-scope atomic loads
// (bypass stale L1/L2). Tag and payload are atomic in a single dword, so no
// fences are needed anywhere in the loop. Two exchange buffers ping-pong by
// step parity to prevent fast writers overwriting data slow readers still
// need. Each block keeps its own 16 rows of h in fp32 registers across
// steps (full-precision leak chain); fp16 is only the matvec exchange
// format. Wh lives in LDS as fp16 (128 KB), staged once.

#define T_STEPS  4096
#define R_SIZE   4096
#define I_SIZE   3
#define OUT_COLS (R_SIZE + I_SIZE)   // 4099
#define NB       256                 // blocks == CUs; all co-resident
#define BT       256                 // threads per block (4 waves)
#define RPB      16                  // rows per block
#define RPW      4                   // rows per wave
#define WPT      (R_SIZE / BT)       // 16 exchange words per thread
#define LEAK     0.1f

typedef _Float16 h2 __attribute__((ext_vector_type(2)));
typedef _Float16 h4 __attribute__((ext_vector_type(4)));
typedef _Float16 h8 __attribute__((ext_vector_type(8)));

__device__ __forceinline__ float fdot2f(h2 a, h2 b, float c) {
#if __has_builtin(__builtin_amdgcn_fdot2)
    return __builtin_amdgcn_fdot2(a, b, c, false);
#else
    return c + (float)a[0] * (float)b[0] + (float)a[1] * (float)b[1];
#endif
}

__global__ void __launch_bounds__(BT, 1) esn_kernel(
    const float* __restrict__ Wh,   // [R, R] row-major fp32
    const float* __restrict__ Win,  // [R, 3]
    const float* __restrict__ x,    // [T, 3]
    float* __restrict__ out,        // [T, 4099]
    unsigned* __restrict__ ex0,     // exchange buf, even steps (R dwords)
    unsigned* __restrict__ ex1)     // exchange buf, odd steps  (R dwords)
{
    __shared__ alignas(16) _Float16 whl[RPB][R_SIZE];  // 128 KB
    __shared__ alignas(16) _Float16 hl[R_SIZE];        // 8 KB
    __shared__ float winl[RPB][3];

    const int tid  = threadIdx.x;
    const int bid  = blockIdx.x;
    const int wv   = tid >> 6;
    const int lane = tid & 63;
    const int r0   = bid * RPB;

    // ---- one-time: stage this block's 16 Wh rows into LDS as fp16 ----
    for (int rr = 0; rr < RPB; ++rr) {
        const float4* src = (const float4*)(Wh + (size_t)(r0 + rr) * R_SIZE);
        h4* dst = (h4*)&whl[rr][0];
        #pragma unroll
        for (int jj = 0; jj < R_SIZE / 4 / BT; ++jj) {   // 4 iters
            int i4 = jj * BT + tid;
            float4 v = src[i4];
            h4 hv;
            hv[0] = (_Float16)v.x; hv[1] = (_Float16)v.y;
            hv[2] = (_Float16)v.z; hv[3] = (_Float16)v.w;
            dst[i4] = hv;
        }
    }
    if (tid < RPB * I_SIZE) {
        int rr = tid / I_SIZE, c = tid % I_SIZE;
        winl[rr][c] = Win[(size_t)(r0 + rr) * I_SIZE + c];
    }
    __syncthreads();

    // own-row fp32 state (meaningful on lanes 0..3 of each wave); h0 = 0
    float hown = 0.0f;

    for (int t = 0; t < T_STEPS; ++t) {
        unsigned* __restrict__ exr = (t & 1) ? ex1 : ex0;   // read: tag == t
        unsigned* __restrict__ exw = (t & 1) ? ex0 : ex1;   // write: tag t+1

        const float xt0 = x[t * 3 + 0];
        const float xt1 = x[t * 3 + 1];
        const float xt2 = x[t * 3 + 2];

        // ---- poll exchange: 16 dwords per thread, tag must equal t ----
        // (at t=0 the memset'd zero words parse as tag 0, h = 0.0 — correct)
        unsigned w[WPT];
        const unsigned tagexp = (unsigned)t;
        #pragma unroll
        for (int k = 0; k < WPT; ++k)
            w[k] = __hip_atomic_load(&exr[k * BT + tid],
                                     __ATOMIC_RELAXED, __HIP_MEMORY_SCOPE_AGENT);
        unsigned pend = 0;
        #pragma unroll
        for (int k = 0; k < WPT; ++k)
            if ((w[k] >> 16) != tagexp) pend |= 1u << k;
        while (pend) {
            __builtin_amdgcn_s_sleep(1);
            #pragma unroll
            for (int k = 0; k < WPT; ++k) {
                if (pend & (1u << k)) {
                    w[k] = __hip_atomic_load(&exr[k * BT + tid],
                                             __ATOMIC_RELAXED, __HIP_MEMORY_SCOPE_AGENT);
                    if ((w[k] >> 16) == tagexp) pend &= ~(1u << k);
                }
            }
        }
        #pragma unroll
        for (int k = 0; k < WPT; ++k)
            hl[k * BT + tid] =
                __builtin_bit_cast(_Float16, (unsigned short)(w[k] & 0xffffu));
        __syncthreads();

        // ---- per-lane h chunk into registers (reused across 4 rows) ----
        h8 hreg[8];
        const h8* hl8 = (const h8*)hl;
        #pragma unroll
        for (int j = 0; j < 8; ++j) hreg[j] = hl8[j * 64 + lane];

        // ---- 4 rows per wave: LDS-stream Wh, dot2-accumulate ----
        float acc[RPW];
        #pragma unroll
        for (int rr = 0; rr < RPW; ++rr) {
            const h8* wrow = (const h8*)&whl[wv * RPW + rr][0];
            float a = 0.0f;
            #pragma unroll
            for (int j = 0; j < 8; ++j) {
                h8 w8 = wrow[j * 64 + lane];
                h8 hh = hreg[j];
                a = fdot2f(__builtin_shufflevector(w8, w8, 0, 1),
                           __builtin_shufflevector(hh, hh, 0, 1), a);
                a = fdot2f(__builtin_shufflevector(w8, w8, 2, 3),
                           __builtin_shufflevector(hh, hh, 2, 3), a);
                a = fdot2f(__builtin_shufflevector(w8, w8, 4, 5),
                           __builtin_shufflevector(hh, hh, 4, 5), a);
                a = fdot2f(__builtin_shufflevector(w8, w8, 6, 7),
                           __builtin_shufflevector(hh, hh, 6, 7), a);
            }
            #pragma unroll
            for (int s = 32; s; s >>= 1) a += __shfl_xor(a, s, 64);
            acc[rr] = a;   // butterfly: all lanes hold the row sum
        }

        // ---- epilogue: lanes 0..3 of each wave finish + publish one row ----
        // NOTE: no trailing __syncthreads needed — a wave can only reach the
        // next step's hl overwrite after its poll sees tag t+1 from ALL
        // blocks, which requires every wave here to have published; and each
        // wave's hreg load (its only hl read) precedes its own publish.
        if (lane < RPW) {
            int rr = wv * RPW + lane;
            float a = (lane == 0) ? acc[0]
                    : (lane == 1) ? acc[1]
                    : (lane == 2) ? acc[2] : acc[3];
            float u  = xt0 * winl[rr][0] + xt1 * winl[rr][1] + xt2 * winl[rr][2];
            float hn = tanhf(u + a);
            float hv = LEAK * hown + (1.0f - LEAK) * hn;   // fp32 leak chain
            hown = hv;
            int r = r0 + rr;
            out[(size_t)t * OUT_COLS + r] = hv;
            _Float16 hf = (_Float16)hv;
            unsigned word = ((unsigned)(t + 1) << 16) |
                            (unsigned)__builtin_bit_cast(unsigned short, hf);
            __hip_atomic_store(&exw[r], word,
                               __ATOMIC_RELAXED, __HIP_MEMORY_SCOPE_AGENT);
        }
    }
}

__global__ void copy_x_kernel(const float* __restrict__ x, float* __restrict__ out) {
    int i = blockIdx.x * blockDim.x + threadIdx.x;
    if (i < T_STEPS * I_SIZE) {
        int t = i / I_SIZE, c = i % I_SIZE;
        out[(size_t)t * OUT_COLS + R_SIZE + c] = x[i];
    }
}

extern "C" void kernel_launch(void* const* d_in, const int* in_sizes, int n_in,
                              void* d_out, int out_size, void* d_ws, size_t ws_size,
                              hipStream_t stream) {
    // setup_inputs order: x [T,3], Win [R,3], Wh [R,R]; all fp32.
    const float* x   = (const float*)d_in[0];
    const float* Win = (const float*)d_in[1];
    const float* Wh  = (const float*)d_in[2];
    float* out = (float*)d_out;

    // ws layout: two exchange buffers of R dwords each (32 KB total).
    unsigned* ex0 = (unsigned*)d_ws;
    unsigned* ex1 = ex0 + R_SIZE;

    // zero both exchange buffers: buf0 all-zero == (tag 0, h=0) = initial
    // state for step 0; buf1 all-zero == tag 0 != 1, so step-1 readers wait.
    hipMemsetAsync(d_ws, 0, 2 * R_SIZE * sizeof(unsigned), stream);

    copy_x_kernel<<<dim3((T_STEPS * I_SIZE + BT - 1) / BT), dim3(BT), 0, stream>>>(x, out);

    void* args[] = {(void*)&Wh, (void*)&Win, (void*)&x, (void*)&out,
                    (void*)&ex0, (void*)&ex1};
    hipError_t e = hipLaunchCooperativeKernel((void*)esn_kernel, dim3(NB), dim3(BT),
                                              args, 0, stream);
    if (e != hipSuccess) {
        // Fallback: plain launch. 139 KB LDS forces 1 block/CU and grid==CU
        // count, so all 256 blocks are co-resident in practice.
        esn_kernel<<<dim3(NB), dim3(BT), 0, stream>>>(Wh, Win, x, out, ex0, ex1);
    }
}

// Round 3
// 16304.622 us; speedup vs baseline: 5.1607x; 1.5062x over previous
//
#include <hip/hip_runtime.h>
#include <cmath>

// ESN forward scan on MI355X — round 3.
// Round-2 lesson (rocprof): VALUBusy 9.4% -> compute ~0.6 us/step, but 6
// us/step total. The re-poll loop's per-word data-dependent branches made
// the compiler serialize 16 L3-latency loads per round (~4.8 us). Fixes:
//   1. Batched poll: 4x inline-asm global_load_dwordx4 sc0 sc1 (L1/L2
//      bypass), ONE s_waitcnt, then check all 16 tags. Round ~0.35 us.
//   2. Register-resident weights: each thread keeps its 4 rows x 64 elems
//      of Wh as fp16 in 128 VGPRs (one-time preload). No 128 KB/step LDS
//      stream; LDS is just the 8 KB h buffer.
// Exchange protocol unchanged from round 2: word = (tag<<16)|fp16(h),
// relaxed AGENT atomic stores publish, ping-pong buffers by step parity,
// no fences (tag+payload atomic in one dword).

#define T_STEPS  4096
#define R_SIZE   4096
#define I_SIZE   3
#define OUT_COLS (R_SIZE + I_SIZE)   // 4099
#define NB       256                 // blocks == CUs; all co-resident
#define BT       256                 // threads per block (4 waves)
#define RPB      16                  // rows per block
#define RPW      4                   // rows per wave
#define LEAK     0.1f

typedef _Float16 h2 __attribute__((ext_vector_type(2)));
typedef _Float16 h4 __attribute__((ext_vector_type(4)));
typedef _Float16 h8 __attribute__((ext_vector_type(8)));
typedef unsigned u32x4 __attribute__((ext_vector_type(4)));

__device__ __forceinline__ float fdot2f(h2 a, h2 b, float c) {
#if __has_builtin(__builtin_amdgcn_fdot2)
    return __builtin_amdgcn_fdot2(a, b, c, false);
#else
    return c + (float)a[0] * (float)b[0] + (float)a[1] * (float)b[1];
#endif
}

// 16 tagged words in flight with L1/L2 bypass, one waitcnt.
__device__ __forceinline__ void poll16(const unsigned* p0, const unsigned* p1,
                                       const unsigned* p2, const unsigned* p3,
                                       u32x4& a0, u32x4& a1, u32x4& a2, u32x4& a3) {
    asm volatile(
        "global_load_dwordx4 %0, %4, off sc0 sc1\n\t"
        "global_load_dwordx4 %1, %5, off sc0 sc1\n\t"
        "global_load_dwordx4 %2, %6, off sc0 sc1\n\t"
        "global_load_dwordx4 %3, %7, off sc0 sc1\n\t"
        "s_waitcnt vmcnt(0)"
        : "=&v"(a0), "=&v"(a1), "=&v"(a2), "=&v"(a3)
        : "v"(p0), "v"(p1), "v"(p2), "v"(p3)
        : "memory");
}

__device__ __forceinline__ _Float16 lo_half(unsigned w) {
    return __builtin_bit_cast(_Float16, (unsigned short)(w & 0xffffu));
}

__global__ void __launch_bounds__(BT, 1) esn_kernel(
    const float* __restrict__ Wh,   // [R, R] row-major fp32
    const float* __restrict__ Win,  // [R, 3]
    const float* __restrict__ x,    // [T, 3]
    float* __restrict__ out,        // [T, 4099]
    unsigned* __restrict__ ex0,     // exchange buf, even-step reads (R dwords)
    unsigned* __restrict__ ex1)     // exchange buf, odd-step reads  (R dwords)
{
    __shared__ alignas(16) _Float16 hl[R_SIZE];   // 8 KB

    const int tid  = threadIdx.x;
    const int bid  = blockIdx.x;
    const int wv   = tid >> 6;
    const int lane = tid & 63;
    const int r0   = bid * RPB;

    // ---- one-time: this wave's 4 Wh rows -> fp16 registers ----
    // wreg[rr*8+j] holds row (r0+wv*4+rr) elements [(j*64+lane)*8 .. +8)
    h8 wreg[RPW * 8];
    #pragma unroll
    for (int rr = 0; rr < RPW; ++rr) {
        const float* src = Wh + (size_t)(r0 + wv * RPW + rr) * R_SIZE;
        #pragma unroll
        for (int j = 0; j < 8; ++j) {
            int e = (j * 64 + lane) * 8;
            float4 a = *(const float4*)(src + e);
            float4 b = *(const float4*)(src + e + 4);
            h8 hv;
            hv[0] = (_Float16)a.x; hv[1] = (_Float16)a.y;
            hv[2] = (_Float16)a.z; hv[3] = (_Float16)a.w;
            hv[4] = (_Float16)b.x; hv[5] = (_Float16)b.y;
            hv[6] = (_Float16)b.z; hv[7] = (_Float16)b.w;
            wreg[rr * 8 + j] = hv;
        }
    }

    // publisher lanes (lane<4) cache their row's Win and state
    float win0 = 0.f, win1 = 0.f, win2 = 0.f;
    if (lane < RPW) {
        int r = r0 + wv * RPW + lane;
        win0 = Win[(size_t)r * I_SIZE + 0];
        win1 = Win[(size_t)r * I_SIZE + 1];
        win2 = Win[(size_t)r * I_SIZE + 2];
    }
    float hown = 0.0f;   // fp32 leak chain, h0 = 0

    // poll pointers: thread tid owns words {m*1024 + tid*4 .. +3}, m=0..3
    const unsigned* pa[2][4];
    #pragma unroll
    for (int m = 0; m < 4; ++m) {
        pa[0][m] = ex0 + m * 1024 + tid * 4;
        pa[1][m] = ex1 + m * 1024 + tid * 4;
    }

    for (int t = 0; t < T_STEPS; ++t) {
        const int par = t & 1;
        unsigned* __restrict__ exw = par ? ex0 : ex1;   // publish tag t+1

        const float xt0 = x[t * 3 + 0];
        const float xt1 = x[t * 3 + 1];
        const float xt2 = x[t * 3 + 2];

        // ---- batched poll: all 16 words, tag must equal t ----
        u32x4 a0, a1, a2, a3;
        const unsigned tg = (unsigned)t;
        for (;;) {
            poll16(pa[par][0], pa[par][1], pa[par][2], pa[par][3],
                   a0, a1, a2, a3);
            bool ok = (a0[0] >> 16) == tg && (a0[1] >> 16) == tg &&
                      (a0[2] >> 16) == tg && (a0[3] >> 16) == tg &&
                      (a1[0] >> 16) == tg && (a1[1] >> 16) == tg &&
                      (a1[2] >> 16) == tg && (a1[3] >> 16) == tg &&
                      (a2[0] >> 16) == tg && (a2[1] >> 16) == tg &&
                      (a2[2] >> 16) == tg && (a2[3] >> 16) == tg &&
                      (a3[0] >> 16) == tg && (a3[1] >> 16) == tg &&
                      (a3[2] >> 16) == tg && (a3[3] >> 16) == tg;
            if (ok) break;
            __builtin_amdgcn_s_sleep(1);
        }

        // ---- unpack to LDS (8 B per thread per chunk) ----
        {
            u32x4 aa[4] = {a0, a1, a2, a3};
            #pragma unroll
            for (int m = 0; m < 4; ++m) {
                h4 hv;
                hv[0] = lo_half(aa[m][0]); hv[1] = lo_half(aa[m][1]);
                hv[2] = lo_half(aa[m][2]); hv[3] = lo_half(aa[m][3]);
                *(h4*)&hl[m * 1024 + tid * 4] = hv;
            }
        }
        __syncthreads();

        // ---- per-lane h chunk into registers ----
        h8 hreg[8];
        const h8* hl8 = (const h8*)hl;
        #pragma unroll
        for (int j = 0; j < 8; ++j) hreg[j] = hl8[j * 64 + lane];

        // ---- 4 rows per wave: register weights, dot2-accumulate ----
        float acc[RPW];
        #pragma unroll
        for (int rr = 0; rr < RPW; ++rr) {
            float a = 0.0f;
            #pragma unroll
            for (int j = 0; j < 8; ++j) {
                h8 w8 = wreg[rr * 8 + j];
                h8 hh = hreg[j];
                a = fdot2f(__builtin_shufflevector(w8, w8, 0, 1),
                           __builtin_shufflevector(hh, hh, 0, 1), a);
                a = fdot2f(__builtin_shufflevector(w8, w8, 2, 3),
                           __builtin_shufflevector(hh, hh, 2, 3), a);
                a = fdot2f(__builtin_shufflevector(w8, w8, 4, 5),
                           __builtin_shufflevector(hh, hh, 4, 5), a);
                a = fdot2f(__builtin_shufflevector(w8, w8, 6, 7),
                           __builtin_shufflevector(hh, hh, 6, 7), a);
            }
            #pragma unroll
            for (int s = 32; s; s >>= 1) a += __shfl_xor(a, s, 64);
            acc[rr] = a;
        }

        // ---- epilogue: lanes 0..3 finish + publish one row each ----
        // Barrier-free safety: a wave reaches the next step's hl overwrite
        // only after its poll sees tag t+1 from ALL blocks, which requires
        // its own sibling waves to have published step t — and each wave's
        // last hl read (hreg load) precedes its own publish.
        if (lane < RPW) {
            float a = (lane == 0) ? acc[0]
                    : (lane == 1) ? acc[1]
                    : (lane == 2) ? acc[2] : acc[3];
            float u  = xt0 * win0 + xt1 * win1 + xt2 * win2;
            float hn = tanhf(u + a);
            float hv = LEAK * hown + (1.0f - LEAK) * hn;
            hown = hv;
            int r = r0 + wv * RPW + lane;
            out[(size_t)t * OUT_COLS + r] = hv;
            _Float16 hf = (_Float16)hv;
            unsigned word = ((unsigned)(t + 1) << 16) |
                            (unsigned)__builtin_bit_cast(unsigned short, hf);
            __hip_atomic_store(&exw[r], word,
                               __ATOMIC_RELAXED, __HIP_MEMORY_SCOPE_AGENT);
        }
    }
}

__global__ void copy_x_kernel(const float* __restrict__ x, float* __restrict__ out) {
    int i = blockIdx.x * blockDim.x + threadIdx.x;
    if (i < T_STEPS * I_SIZE) {
        int t = i / I_SIZE, c = i % I_SIZE;
        out[(size_t)t * OUT_COLS + R_SIZE + c] = x[i];
    }
}

extern "C" void kernel_launch(void* const* d_in, const int* in_sizes, int n_in,
                              void* d_out, int out_size, void* d_ws, size_t ws_size,
                              hipStream_t stream) {
    // setup_inputs order: x [T,3], Win [R,3], Wh [R,R]; all fp32.
    const float* x   = (const float*)d_in[0];
    const float* Win = (const float*)d_in[1];
    const float* Wh  = (const float*)d_in[2];
    float* out = (float*)d_out;

    // ws layout: two exchange buffers of R dwords each (32 KB total).
    unsigned* ex0 = (unsigned*)d_ws;
    unsigned* ex1 = ex0 + R_SIZE;

    // zero both exchange buffers: ex0 all-zero == (tag 0, h=0) = initial
    // state for step 0; ex1 all-zero == tag 0 != 1, so step-1 readers wait.
    hipMemsetAsync(d_ws, 0, 2 * R_SIZE * sizeof(unsigned), stream);

    copy_x_kernel<<<dim3((T_STEPS * I_SIZE + BT - 1) / BT), dim3(BT), 0, stream>>>(x, out);

    void* args[] = {(void*)&Wh, (void*)&Win, (void*)&x, (void*)&out,
                    (void*)&ex0, (void*)&ex1};
    hipError_t e = hipLaunchCooperativeKernel((void*)esn_kernel, dim3(NB), dim3(BT),
                                              args, 0, stream);
    if (e != hipSuccess) {
        // Fallback: plain launch; 256 blocks x 4 waves always co-resident.
        esn_kernel<<<dim3(NB), dim3(BT), 0, stream>>>(Wh, Win, x, out, ex0, ex1);
    }
}